// Round 10
// baseline (284.127 us; speedup 1.0000x reference)
//
#include <hip/hip_runtime.h>
#include <hip/hip_bf16.h>

#define B_ 4096
#define D_ 32
#define H_ 1024
#define CS 512                 // activation chunk stride: [chunk][16 rows][32] shorts
#define WPK2_L 1171456         // shorts per padded layer pack (2048 * 4 * 143)

typedef __attribute__((ext_vector_type(8))) short short8;
typedef __attribute__((ext_vector_type(4))) float floatx4;

// non-draining workgroup barrier: LDS visibility only, leaves global loads in flight
#define BAR() __asm__ __volatile__("s_waitcnt lgkmcnt(0)\n\ts_barrier" ::: "memory")

__device__ inline unsigned short f2bf(float f) {      // fp32 -> bf16 bits, RNE
    unsigned u = __float_as_uint(f);
    unsigned r = (u + 0x7FFF + ((u >> 16) & 1)) >> 16;
    return (unsigned short)r;
}

// degree-sorted order: degree 0 -> slots [0,34), degree d>=1 -> slots [33d+1, 33d+34)
__device__ inline int degs(int hp) { return (hp < 34) ? 0 : (hp - 1) / 33; }
__device__ inline int permf(int hp) {                  // sorted slot -> original h
    int d = degs(hp);
    int r = d ? (hp - 33 * d - 1) : hp;
    return d + 31 * r;
}
__device__ inline int band0i(int idx) {                // fresh-band base slot at step idx>=1
    int nb0 = (idx == 1) ? 0 : 33 * idx - 32;
    return (nb0 > H_ - 64) ? H_ - 64 : nb0;
}

// ---- prep stage 1 (fused): permuted+masked Wbp, W0 packs, Wout packs, biases ----
__global__ __launch_bounds__(256) void prep1(
        const float* __restrict__ Wh, const float* __restrict__ W0,
        const float* __restrict__ Wout, const float* __restrict__ b0,
        const float* __restrict__ bh,
        unsigned short* __restrict__ Wbp, unsigned short* __restrict__ W0pk,
        unsigned short* __restrict__ Wopk, float* __restrict__ b0p,
        float* __restrict__ bhp) {
    __shared__ float row[H_];
    int b = blockIdx.x, t = threadIdx.x;
    if (b < 2048) {                          // Wbp[l][np][kp], staged via LDS (coalesced)
        int l = b >> 10, np = b & 1023;
        const float* src = Wh + ((size_t)l << 20) + ((size_t)permf(np) << 10);
        ((float4*)row)[t] = ((const float4*)src)[t];
        __syncthreads();
        int dn = degs(np);
        unsigned short o[4];
        #pragma unroll
        for (int j = 0; j < 4; j++) {
            int kp = t * 4 + j;
            o[j] = (dn >= degs(kp)) ? f2bf(row[permf(kp)]) : (unsigned short)0;
        }
        ((ushort4*)(Wbp + ((size_t)l << 20) + ((size_t)np << 10)))[t] =
            ushort4{o[0], o[1], o[2], o[3]};
    } else if (b < 2079) {                   // W0 band packs [idx][slot64][32]
        int idx = b - 2047;
        int nb0 = band0i(idx);
        int j = t >> 2, ko = (t & 3) * 8;
        int n = nb0 + j;
        int dn = degs(n);
        const float* srow = W0 + (size_t)permf(n) * 32;
        union { unsigned short o[8]; uint4 v; } u;
        #pragma unroll
        for (int e = 0; e < 8; e++)
            u.o[e] = (dn >= ko + e) ? f2bf(srow[ko + e]) : (unsigned short)0;
        *(uint4*)(W0pk + (idx - 1) * 2048 + j * 32 + ko) = u.v;
    } else if (b < 3103) {                   // Wout bf16 packs [idx][c][col16][32], full prefix
        int bb = b - 2079;
        int idx = bb >> 5, c = bb & 31;
        int ns = idx ? 33 * idx + 1 : 0;     // live-prefix length at step idx
        #pragma unroll
        for (int uu = 0; uu < 2; uu++) {
            int e = t + uu * 256;
            int col = e >> 5, k = e & 31;
            int h = c * 32 + k;
            unsigned short v = 0;
            if (col < 2 && h < ns)
                v = f2bf(Wout[(size_t)(idx + col * 32) * H_ + permf(h)]);
            Wopk[(size_t)bb * 512 + e] = v;
        }
    } else {                                 // biases
        int tt = (b - 3103) * 256 + t;
        int hp = tt & 1023;
        int p = permf(hp);
        if (tt < 1024) b0p[hp] = b0[p];
        else if (tt < 2048) bhp[hp] = bh[p];
        else bhp[1024 + hp] = bh[1024 + p];
    }
}

// ---- prep stage 2: repack Wbp -> padded per-step band packs [c][slot64][32] ----
// nkp(idx) = 4*ceil((idx+1)/4) chunks; chunks beyond nk = idx+1 are all-zero (exact).
__global__ __launch_bounds__(256) void prep2(const unsigned short* __restrict__ Wbp,
                                             unsigned short* __restrict__ Wpk) {
    int b = blockIdx.x;                      // 2 layers * 31 idx * 32 chunk slots
    int l = b / 992;
    int r = b - l * 992;
    int idx = (r >> 5) + 1;
    int c = r & 31;
    int Cn = (idx + 4) >> 2;                 // = ceil((idx+1)/4)
    if (c >= 4 * Cn) return;
    int S = 0;
    for (int j = 1; j < idx; j++) S += (j + 4) >> 2;
    size_t base = (size_t)l * WPK2_L + (size_t)S * 4 * 2048 + (size_t)c * 2048;
    int t = threadIdx.x;
    int j = t >> 2, ko = (t & 3) * 8;
    uint4 v = {0u, 0u, 0u, 0u};
    if (c <= idx) {                          // live chunk: copy; else leave zero pad
        int nb0 = band0i(idx);
        v = *(const uint4*)(Wbp + ((size_t)l << 20) + ((size_t)(nb0 + j) << 10) + c * 32 + ko);
    }
    *(uint4*)(Wpk + base + j * 32 + ko) = v;
}

__device__ inline floatx4 mfma16(short8 a, short8 b, floatx4 c) {
    return __builtin_amdgcn_mfma_f32_16x16x32_bf16(a, b, c, 0, 0, 0);
}

// ---- one autoregressive step, K-depth C chunks per wave (compile-time) ----
template <int C>
__device__ __forceinline__ void step_body(
        int idx, int wbase,
        const unsigned short* __restrict__ W0pk, const float* __restrict__ b0p,
        const unsigned short* __restrict__ Wpk, const float* __restrict__ bhp,
        const unsigned short* __restrict__ Wopk, const float* __restrict__ bout,
        const float* zsS, unsigned short* a1, unsigned short* a2, unsigned short* a3,
        unsigned short* xbS, float* xsS, floatx4* redS, float* redO,
        int tid, int wave, int lane, int frow, int fk, int s, int q) {
    const int nb0 = band0i(idx);
    const int arow = frow * 32 + fk * 8;
    const int slot = nb0 + s * 16 + frow;
    const int wsl = (slot >> 5) * CS + (slot & 31);
    const int cbase = q * C;
    const unsigned short* wb2 = Wpk + wbase;
    const unsigned short* wb3 = wb2 + WPK2_L;
    const int woff = s * 512 + frow * 32 + fk * 8;

    // ---- issue L2 weight + out-weight loads (stay in flight across BARs) ----
    short8 wA[C];
    #pragma unroll
    for (int u = 0; u < C; u++)
        wA[u] = *(const short8*)(wb2 + (size_t)(cbase + u) * 2048 + woff);
    const int ca = wave * 2, cb = ca + 1;
    short8 woA = {}, woB = {};
    if (ca <= idx) woA = *(const short8*)(Wopk + (size_t)(idx * 32 + ca) * 512 + frow * 32 + fk * 8);
    if (cb <= idx) woB = *(const short8*)(Wopk + (size_t)(idx * 32 + cb) * 512 + frow * 32 + fk * 8);

    // ---- L1 band: wave 0 alone (reads xbS it wrote last step; all 4 quarters) ----
    if (wave == 0) {
        short8 a = *(const short8*)(xbS + frow * 32 + fk * 8);
        #pragma unroll
        for (int t4 = 0; t4 < 4; t4++) {
            short8 b = *(const short8*)(W0pk + (idx - 1) * 2048 + (t4 * 16 + frow) * 32 + fk * 8);
            floatx4 acc = {0.f, 0.f, 0.f, 0.f};
            acc = mfma16(a, b, acc);
            int sl = nb0 + t4 * 16 + frow;
            int ws2 = (sl >> 5) * CS + (sl & 31);
            float bb = b0p[sl];
            #pragma unroll
            for (int r = 0; r < 4; r++)
                a1[ws2 + (fk * 4 + r) * 32] = f2bf(fmaxf(acc[r] + bb, 0.f));
        }
    }
    BAR();                                             // A: a1 band visible

    // ---- L2 band partials ----
    {
        floatx4 p = {0.f, 0.f, 0.f, 0.f}, p2 = {0.f, 0.f, 0.f, 0.f};
        #pragma unroll
        for (int u = 0; u < C; u++) {
            short8 a = *(const short8*)(a1 + (cbase + u) * CS + arow);
            if (u & 1) p2 = mfma16(a, wA[u], p2); else p = mfma16(a, wA[u], p);
        }
        p = p + p2;
        if (q) redS[((q - 1) * 4 + s) * 64 + lane] = p;
        // issue L3 weight loads now: hidden behind BAR B + combine + BAR C
        short8 wB[C];
        #pragma unroll
        for (int u = 0; u < C; u++)
            wB[u] = *(const short8*)(wb3 + (size_t)(cbase + u) * 2048 + woff);
        BAR();                                         // B: partials visible
        if (q == 0) {
            p = p + redS[s * 64 + lane] + redS[(4 + s) * 64 + lane] + redS[(8 + s) * 64 + lane];
            float bb = bhp[slot];
            #pragma unroll
            for (int r = 0; r < 4; r++)
                a2[wsl + (fk * 4 + r) * 32] = f2bf(fmaxf(p[r] + bb, 0.f));
        }
        BAR();                                         // C: a2 band visible

        // ---- L3 band partials ----
        floatx4 g = {0.f, 0.f, 0.f, 0.f}, g2 = {0.f, 0.f, 0.f, 0.f};
        #pragma unroll
        for (int u = 0; u < C; u++) {
            short8 a = *(const short8*)(a2 + (cbase + u) * CS + arow);
            if (u & 1) g2 = mfma16(a, wB[u], g2); else g = mfma16(a, wB[u], g);
        }
        g = g + g2;
        if (q) redS[((q - 1) * 4 + s) * 64 + lane] = g;
        BAR();                                         // D: partials visible
        if (q == 0) {
            g = g + redS[s * 64 + lane] + redS[(4 + s) * 64 + lane] + redS[(8 + s) * 64 + lane];
            float bb = bhp[H_ + slot];
            #pragma unroll
            for (int r = 0; r < 4; r++)
                a3[wsl + (fk * 4 + r) * 32] = f2bf(fmaxf(g[r] + bb, 0.f));
        }
    }

    // ---- out-dot: finalized chunks overlap the combine window ----
    floatx4 oacc = {0.f, 0.f, 0.f, 0.f};
    const bool fA = (ca * 32 + 32 <= nb0), fB = (cb * 32 + 32 <= nb0);
    if (ca <= idx && fA)
        oacc = mfma16(*(const short8*)(a3 + ca * CS + arow), woA, oacc);
    if (cb <= idx && fB)
        oacc = mfma16(*(const short8*)(a3 + cb * CS + arow), woB, oacc);
    BAR();                                             // E: fresh a3 band visible
    if (ca <= idx && !fA)
        oacc = mfma16(*(const short8*)(a3 + ca * CS + arow), woA, oacc);
    if (cb <= idx && !fB)
        oacc = mfma16(*(const short8*)(a3 + cb * CS + arow), woB, oacc);
    if (ca <= idx && frow < 2) {
        #pragma unroll
        for (int r = 0; r < 4; r++)
            redO[wave * 32 + frow * 16 + fk * 4 + r] = oacc[r];
    }
    BAR();                                             // F: redO visible

    // ---- x-update on wave 0 (its xbS write feeds its own L1 next step: no barrier) ----
    if (tid < 16) {
        float sm = bout[idx], sl = bout[idx + D_];
        #pragma unroll
        for (int w = 0; w < 16; w++) {
            sm += redO[w * 32 + tid];
            sl += redO[w * 32 + 16 + tid];
        }
        float xi = fmaf(zsS[tid * 32 + idx], expf(sl), sm);
        xsS[tid * 32 + idx] = xi;
        xbS[tid * 32 + idx] = f2bf(xi);
    }
}

// ---- mega-kernel: 256 wgs x 16 rows x 16 waves; 32-step chain in LDS ----
__global__ __launch_bounds__(1024) void mega_kernel(
        const float* __restrict__ z,
        const unsigned short* __restrict__ W0pk,
        const float* __restrict__ b0p,
        const unsigned short* __restrict__ Wpk,
        const float* __restrict__ bhp,
        const unsigned short* __restrict__ Wopk,
        const float* __restrict__ bout,
        float* __restrict__ xout) {
    __shared__ unsigned short aS[3 * 32 * CS];     // a1,a2,a3: [c][16 rows][32], 32KB each
    __shared__ unsigned short xbS[512];            // running x, bf16
    __shared__ float xsS[512];                     // running x, fp32
    __shared__ float zsS[512];
    __shared__ floatx4 redS[12 * 64];              // K-split partials [q-1][s][lane]
    __shared__ float redO[16 * 32];                // out-dot partials [wave][col*16+m]

    const int tid = threadIdx.x;
    const int wave = tid >> 6, lane = tid & 63;
    const int frow = lane & 15, fk = lane >> 4;
    const int s = wave & 3, q = wave >> 2;
    const int m0 = blockIdx.x * 16;

    {   // zero-init (garbage x 0-weight must stay 0; matches x0 = 0)
        uint4 zz = {0u, 0u, 0u, 0u};
        for (int i = tid; i < 3 * 32 * CS / 8; i += 1024) ((uint4*)aS)[i] = zz;
        if (tid < 64)  ((uint4*)xbS)[tid] = zz;
        if (tid < 128) ((uint4*)xsS)[tid] = zz;
        if (tid < 128) ((uint4*)redO)[tid] = zz;
        if (tid < 128) ((float4*)zsS)[tid] = ((const float4*)(z + (size_t)m0 * 32))[tid];
    }
    __syncthreads();

    unsigned short* a1 = aS;
    unsigned short* a2 = aS + 32 * CS;
    unsigned short* a3 = aS + 64 * CS;

    // idx = 0: theta = bias (live prefix empty) — wave 0 only, no barrier needed
    if (tid < 16) {
        float xi = fmaf(zsS[tid * 32], expf(bout[D_]), bout[0]);
        xsS[tid * 32] = xi;
        xbS[tid * 32] = f2bf(xi);
    }

    int wbase = 0;
    for (int idx = 1; idx < 32; idx++) {
        switch ((idx + 4) >> 2) {
        case 1: step_body<1>(idx, wbase, W0pk, b0p, Wpk, bhp, Wopk, bout, zsS,
                             a1, a2, a3, xbS, xsS, redS, redO, tid, wave, lane, frow, fk, s, q); break;
        case 2: step_body<2>(idx, wbase, W0pk, b0p, Wpk, bhp, Wopk, bout, zsS,
                             a1, a2, a3, xbS, xsS, redS, redO, tid, wave, lane, frow, fk, s, q); break;
        case 3: step_body<3>(idx, wbase, W0pk, b0p, Wpk, bhp, Wopk, bout, zsS,
                             a1, a2, a3, xbS, xsS, redS, redO, tid, wave, lane, frow, fk, s, q); break;
        case 4: step_body<4>(idx, wbase, W0pk, b0p, Wpk, bhp, Wopk, bout, zsS,
                             a1, a2, a3, xbS, xsS, redS, redO, tid, wave, lane, frow, fk, s, q); break;
        case 5: step_body<5>(idx, wbase, W0pk, b0p, Wpk, bhp, Wopk, bout, zsS,
                             a1, a2, a3, xbS, xsS, redS, redO, tid, wave, lane, frow, fk, s, q); break;
        case 6: step_body<6>(idx, wbase, W0pk, b0p, Wpk, bhp, Wopk, bout, zsS,
                             a1, a2, a3, xbS, xsS, redS, redO, tid, wave, lane, frow, fk, s, q); break;
        case 7: step_body<7>(idx, wbase, W0pk, b0p, Wpk, bhp, Wopk, bout, zsS,
                             a1, a2, a3, xbS, xsS, redS, redO, tid, wave, lane, frow, fk, s, q); break;
        default: step_body<8>(idx, wbase, W0pk, b0p, Wpk, bhp, Wopk, bout, zsS,
                             a1, a2, a3, xbS, xsS, redS, redO, tid, wave, lane, frow, fk, s, q); break;
        }
        wbase += ((idx + 4) >> 2) * 4 * 2048;
    }

    __syncthreads();
    if (tid < 128)
        ((float4*)(xout + (size_t)m0 * 32))[tid] = ((const float4*)xsS)[tid];
}

extern "C" void kernel_launch(void* const* d_in, const int* in_sizes, int n_in,
                              void* d_out, int out_size, void* d_ws, size_t ws_size,
                              hipStream_t stream) {
    const float* z    = (const float*)d_in[0];
    const float* W0   = (const float*)d_in[1];
    const float* b0   = (const float*)d_in[2];
    const float* Wh   = (const float*)d_in[3];   // [2, H, H]
    const float* bh   = (const float*)d_in[4];   // [2, H]
    const float* Wout = (const float*)d_in[5];   // [64, H]
    const float* bout = (const float*)d_in[6];   // [64]

    float* x = (float*)d_out;                          // [B, D] output
    unsigned short* Wbp  = (unsigned short*)d_ws;      // [2, H, H] permuted+masked bf16
    unsigned short* Wpk  = Wbp + 2 * H_ * H_;          // 2 * WPK2_L padded band packs
    unsigned short* W0pk = Wpk + 2 * WPK2_L;           // 31 * 2048
    unsigned short* Wopk = W0pk + 31 * 2048;           // 32 * 32 * 512
    float* b0p = (float*)(Wopk + 32 * 32 * 512);       // [H]
    float* bhp = b0p + H_;                             // [2, H]

    prep1<<<3115, 256, 0, stream>>>(Wh, W0, Wout, b0, bh, Wbp, W0pk, Wopk, b0p, bhp);
    prep2<<<2 * 31 * 32, 256, 0, stream>>>(Wbp, Wpk);

    mega_kernel<<<B_ / 16, 1024, 0, stream>>>(z, W0pk, b0p, Wpk, bhp, Wopk, bout, x);
}